// Round 1
// baseline (67071.826 us; speedup 1.0000x reference)
//
#include <hip/hip_runtime.h>
#include <cstdint>
#include <cstddef>

#define T_STEPS 512
#define BATCH   64
#define IN_DIM  512
#define HID     768
// BETA = 2/3 -> 1/BETA = 1.5 ; ZETA-GAMMA = 1.2 ; GAMMA = -0.1

__device__ __forceinline__ float sigmoidf(float z) {
    return 1.0f / (1.0f + expf(-z));
}

// grid: 256 blocks (block b owns h-cols {3b,3b+1,3b+2} and gate cols q*768+hc),
// block: 512 threads: r = tid&63 (batch row), q = (tid>>6)&3 (gate), half = tid>>8 (K-split)
__global__ __launch_bounds__(512) void masked_lstm_scan(
    const float* __restrict__ x,        // [T,B,I]
    const float* __restrict__ W,        // [4H,I]
    const float* __restrict__ U,        // [4H,H]
    const float* __restrict__ bias,     // [4H]
    const float* __restrict__ log_alpha,// [H]
    const float* __restrict__ urand,    // [T,H]
    float* __restrict__ out,            // [T,B,H]
    float* __restrict__ hbuf,           // [2,B,H]  (holds h_t * s_{t+1})
    unsigned int* __restrict__ bar)     // grid barrier counter (monotonic)
{
    __shared__ float sU[12 * HID];     // 36864 B  U slice  [cidx=q*3+j][k]
    __shared__ float sW[12 * IN_DIM];  // 24576 B  W slice  [cidx][i]
    __shared__ float sPre[12 * BATCH]; //  3072 B  gate preacts [cidx][r]

    const int tid  = threadIdx.x;
    const int bx   = blockIdx.x;
    const int r    = tid & 63;
    const int q    = (tid >> 6) & 3;
    const int half = tid >> 8;
    const int hc0  = 3 * bx;

    // ---- load this block's U and W slices into LDS (once, reused 512 steps) ----
    for (int idx = tid; idx < 12 * HID; idx += 512) {
        int cidx = idx / HID; int k = idx - cidx * HID;
        int qq = cidx / 3;    int jj = cidx - 3 * qq;
        sU[idx] = U[(size_t)(qq * HID + hc0 + jj) * HID + k];
    }
    for (int idx = tid; idx < 12 * IN_DIM; idx += 512) {
        int cidx = idx / IN_DIM; int k = idx - cidx * IN_DIM;
        int qq = cidx / 3;       int jj = cidx - 3 * qq;
        sW[idx] = W[(size_t)(qq * HID + hc0 + jj) * IN_DIM + k];
    }

    // ---- pointwise-lane persistent state (lanes 0..191: pj=tid>>6, row=r) ----
    const bool pw = (tid < 192);
    const int  pj = tid >> 6;            // 0..2 (== q for these lanes)
    int   hc = 0;
    float c_state = 0.0f, s_cur = 0.0f;
    float b0 = 0.f, b1 = 0.f, b2 = 0.f, b3 = 0.f, la = 0.f;
    if (pw) {
        hc = hc0 + pj;
        b0 = bias[hc];
        b1 = bias[HID + hc];
        b2 = bias[2 * HID + hc];
        b3 = bias[3 * HID + hc];
        la = log_alpha[hc];
        // s for t=0
        float uu = urand[hc];
        float logit = (logf(uu) - log1pf(-uu) + la) * 1.5f;
        s_cur = fminf(fmaxf(1.2f * sigmoidf(logit) - 0.1f, 0.0f), 1.0f);
    }

    // wave-uniform LDS bases (q, half are uniform within a wave)
    const float* sUh = sU + (q * 3) * HID + half * 384;
    const float* sWh = sW + (q * 3) * IN_DIM + half * 256;

    __syncthreads();

    for (int t = 0; t < T_STEPS; ++t) {
        // ---------------- matmul phase: 3 gate-cols per lane ----------------
        const float* hrow = hbuf + (size_t)((t & 1) * BATCH + r) * HID + half * 384;
        const float* xrow = x + ((size_t)t * BATCH + r) * IN_DIM + half * 256;

        float a0 = 0.f, a1 = 0.f, a2 = 0.f;

        // recurrent part: (h_{t-1} * s_t) @ U^T   (s already folded into hbuf)
        #pragma unroll 8
        for (int k = 0; k < 384; k += 4) {
            float4 h4 = *(const float4*)(hrow + k);
            float4 u0 = *(const float4*)(sUh + 0 * HID + k);
            float4 u1 = *(const float4*)(sUh + 1 * HID + k);
            float4 u2 = *(const float4*)(sUh + 2 * HID + k);
            a0 += h4.x * u0.x; a1 += h4.x * u1.x; a2 += h4.x * u2.x;
            a0 += h4.y * u0.y; a1 += h4.y * u1.y; a2 += h4.y * u2.y;
            a0 += h4.z * u0.z; a1 += h4.z * u1.z; a2 += h4.z * u2.z;
            a0 += h4.w * u0.w; a1 += h4.w * u1.w; a2 += h4.w * u2.w;
        }
        // input projection part: x_t @ W^T (fused, avoids materializing x_proj)
        #pragma unroll 8
        for (int k = 0; k < 256; k += 4) {
            float4 h4 = *(const float4*)(xrow + k);
            float4 u0 = *(const float4*)(sWh + 0 * IN_DIM + k);
            float4 u1 = *(const float4*)(sWh + 1 * IN_DIM + k);
            float4 u2 = *(const float4*)(sWh + 2 * IN_DIM + k);
            a0 += h4.x * u0.x; a1 += h4.x * u1.x; a2 += h4.x * u2.x;
            a0 += h4.y * u0.y; a1 += h4.y * u1.y; a2 += h4.y * u2.y;
            a0 += h4.z * u0.z; a1 += h4.z * u1.z; a2 += h4.z * u2.z;
            a0 += h4.w * u0.w; a1 += h4.w * u1.w; a2 += h4.w * u2.w;
        }

        // ---------------- reduce the 2 K-halves through LDS ----------------
        if (half == 0) {
            sPre[(q * 3 + 0) * 64 + r] = a0;
            sPre[(q * 3 + 1) * 64 + r] = a1;
            sPre[(q * 3 + 2) * 64 + r] = a2;
        }
        __syncthreads();
        if (half == 1) {
            sPre[(q * 3 + 0) * 64 + r] += a0;
            sPre[(q * 3 + 1) * 64 + r] += a1;
            sPre[(q * 3 + 2) * 64 + r] += a2;
        }
        __syncthreads();

        // ---------------- pointwise LSTM update (owner lanes) ----------------
        if (pw) {
            float p0 = sPre[(0 * 3 + pj) * 64 + r] + b0;
            float p1 = sPre[(1 * 3 + pj) * 64 + r] + b1;
            float p2 = sPre[(2 * 3 + pj) * 64 + r] + b2;
            float p3 = sPre[(3 * 3 + pj) * 64 + r] + b3;
            float s = s_cur;
            p0 *= s; p1 *= s; p2 *= s; p3 *= s;
            float ig = sigmoidf(p0) * s;
            float fg = sigmoidf(p1) * s;
            float cg = tanhf(p2) * s;
            float og = sigmoidf(p3) * s;
            c_state = fg * c_state + ig * cg;
            float h = og * tanhf(c_state);
            out[((size_t)t * BATCH + r) * HID + hc] = h;
            if (t + 1 < T_STEPS) {
                // fold NEXT step's s into the h we publish: hbuf = h_t * s_{t+1}
                float uu = urand[(size_t)(t + 1) * HID + hc];
                float logit = (logf(uu) - log1pf(-uu) + la) * 1.5f;
                float sn = fminf(fmaxf(1.2f * sigmoidf(logit) - 0.1f, 0.0f), 1.0f);
                hbuf[(size_t)(((t + 1) & 1) * BATCH + r) * HID + hc] = h * sn;
                s_cur = sn;
            }
        }

        // ---------------- grid barrier (skip after last step) ----------------
        if (t + 1 < T_STEPS) {
            __threadfence();      // release h stores device-wide (each thread)
            __syncthreads();      // all threads' fences done before arrival
            if (tid == 0) {
                __hip_atomic_fetch_add(bar, 1u, __ATOMIC_RELEASE, __HIP_MEMORY_SCOPE_AGENT);
                unsigned tgt = (unsigned)(t + 1) * gridDim.x;
                while (__hip_atomic_load(bar, __ATOMIC_RELAXED, __HIP_MEMORY_SCOPE_AGENT) < tgt) {
                    __builtin_amdgcn_s_sleep(2);
                }
            }
            __syncthreads();
            __threadfence();      // acquire: invalidate L1/L2 stale lines
        }
    }
}

extern "C" void kernel_launch(void* const* d_in, const int* in_sizes, int n_in,
                              void* d_out, int out_size, void* d_ws, size_t ws_size,
                              hipStream_t stream) {
    const float* x  = (const float*)d_in[0];
    const float* W  = (const float*)d_in[1];
    const float* U  = (const float*)d_in[2];
    const float* b  = (const float*)d_in[3];
    const float* la = (const float*)d_in[4];
    const float* u  = (const float*)d_in[5];
    float* out = (float*)d_out;

    const size_t hbuf_bytes = (size_t)2 * BATCH * HID * sizeof(float); // 393216
    float* hbuf = (float*)d_ws;
    unsigned int* bar = (unsigned int*)((char*)d_ws + hbuf_bytes);

    // zero h0 double-buffer + barrier counter (ws is re-poisoned before every call)
    hipMemsetAsync(d_ws, 0, hbuf_bytes + 64, stream);

    hipLaunchKernelGGL(masked_lstm_scan, dim3(256), dim3(512), 0, stream,
                       x, W, U, b, la, u, out, hbuf, bar);
}

// Round 2
// 19062.489 us; speedup vs baseline: 3.5185x; 3.5185x over previous
//
#include <hip/hip_runtime.h>
#include <cstdint>
#include <cstddef>

#define T_STEPS 512
#define BATCH   64
#define IN_DIM  512
#define HID     768
#define G4H     3072
#define SH_STRIDE 392   // 384 + 8 pad: spreads banks for staging writes

typedef __attribute__((ext_vector_type(8))) short bf16x8;
typedef __attribute__((ext_vector_type(4))) float f32x4;

__device__ __forceinline__ float sigmoidf_(float z){ return 1.0f/(1.0f+expf(-z)); }
__device__ __forceinline__ float bf16_to_f32(unsigned short u){
    return __uint_as_float(((unsigned int)u) << 16);
}
__device__ __forceinline__ unsigned short f32_to_bf16_rne(float v){
    unsigned int bits = __float_as_uint(v);
    unsigned int lsb = (bits >> 16) & 1u;
    bits += 0x7fffu + lsb;
    return (unsigned short)(bits >> 16);
}

// ---------------- phase 1a: fp32 -> bf16 conversion ----------------
__global__ void cvt_bf16_kernel(const float* __restrict__ in, unsigned short* __restrict__ out, int n){
    int i = blockIdx.x*256 + threadIdx.x;
    if (i < n) out[i] = f32_to_bf16_rne(in[i]);
}

// ---------------- phase 1b: x_proj = x @ W^T via bf16 MFMA ----------------
// A = xbf [32768 x 512], B = wbf [3072 x 512] (both row-major, K contiguous).
// Wave tile 64x64 via 16 x (16x16x32) MFMAs; C row=(lane>>4)*4+reg, col=lane&15.
__global__ __launch_bounds__(256, 4) void xproj_gemm(
    const unsigned short* __restrict__ A, const unsigned short* __restrict__ B,
    unsigned short* __restrict__ Cbf, float* __restrict__ Cf, int store_f32)
{
    const int wave = threadIdx.x >> 6;
    const int lane = threadIdx.x & 63;
    const int tile = blockIdx.x*4 + wave;         // 24576 = 512 x 48
    const int mt = tile & 511;
    const int nt = tile >> 9;
    const long m0 = (long)mt*64, n0 = (long)nt*64;
    const int lr = lane & 15, lq = lane >> 4;

    f32x4 acc[4][4];
    #pragma unroll
    for (int i=0;i<4;i++)
        #pragma unroll
        for (int j=0;j<4;j++) acc[i][j] = (f32x4){0.f,0.f,0.f,0.f};

    const unsigned short* Ap = A + (m0 + lr)*512 + lq*8;
    const unsigned short* Bp = B + (n0 + lr)*512 + lq*8;

    for (int k0 = 0; k0 < 512; k0 += 32){
        bf16x8 a[4], b[4];
        #pragma unroll
        for (int i=0;i<4;i++) a[i] = *(const bf16x8*)(Ap + (long)i*16*512 + k0);
        #pragma unroll
        for (int j=0;j<4;j++) b[j] = *(const bf16x8*)(Bp + (long)j*16*512 + k0);
        #pragma unroll
        for (int i=0;i<4;i++)
            #pragma unroll
            for (int j=0;j<4;j++)
                acc[i][j] = __builtin_amdgcn_mfma_f32_16x16x32_bf16(a[i], b[j], acc[i][j], 0,0,0);
    }

    #pragma unroll
    for (int i=0;i<4;i++)
        #pragma unroll
        for (int j=0;j<4;j++)
            #pragma unroll
            for (int r=0;r<4;r++){
                long row = m0 + 16*i + lq*4 + r;
                long col = n0 + 16*j + lr;
                float v = acc[i][j][r];
                if (store_f32) Cf[row*G4H + col] = v;
                else           Cbf[row*G4H + col] = f32_to_bf16_rne(v);
            }
}

// ---------------- phase 2: persistent scan ----------------
// 256 blocks x 512 threads. bg = bx&1 picks batch half (32 rows); cb = bx>>1
// owns 6 h-cols (24 gate-cols). U slice lives in LDS for all 512 steps.
// h exchange: relaxed AGENT-scope atomics (coherent at MALL, no L2 fences).
// GEMM: register tile 8 rows x 6 cols, K split 32 ways, shuffle-reduce.
__global__ __launch_bounds__(512, 2) void masked_lstm_scan2(
    const float* __restrict__ x, const float* __restrict__ W,
    const float* __restrict__ U, const float* __restrict__ bias,
    const float* __restrict__ log_alpha, const float* __restrict__ urand,
    float* __restrict__ out, float* __restrict__ hb, unsigned int* __restrict__ bar,
    const unsigned short* __restrict__ xpb, const float* __restrict__ xpf, int mode)
{
    __shared__ float sH[32*SH_STRIDE];   // 50176 B staging tile (h or x halves)
    __shared__ float sU[24*HID];         // 73728 B U slice
    __shared__ float sRed[24*32];        //  3072 B reduced preacts

    const int tid = threadIdx.x;
    const int bx  = blockIdx.x;
    const int bg  = bx & 1;
    const int cb  = bx >> 1;             // 0..127
    const int hc0 = 6*cb;
    const int row0 = 32*bg;

    const int ks  = tid & 31;            // K-split lane (within 32-wide segment)
    const int pos = tid >> 5;            // 0..15
    const int rt  = pos & 3;             // row tile (8 rows)
    const int qg  = pos >> 2;            // gate 0..3

    const int sr  = tid >> 4;            // staging row 0..31
    const int skb = (tid & 15)*24;       // staging k base (24 floats/thread)

    const bool own = tid < 192;
    const int orow = tid & 31;
    const int oj   = tid >> 5;           // 0..5
    const int ohc  = hc0 + oj;

    // ---- load U slice (once): sU[c][k], c = q*6+j -> U row q*768+hc0+j
    for (int i4 = tid; i4 < 24*(HID/4); i4 += 512){
        int c  = i4 / (HID/4);
        int k  = (i4 - c*(HID/4))*4;
        int gq = c/6, gj = c - 6*gq;
        *(f32x4*)(sU + c*HID + k) = *(const f32x4*)(U + (size_t)(gq*HID + hc0 + gj)*HID + k);
    }

    float c_state = 0.f, s_cur = 0.f;
    float b0=0.f,b1=0.f,b2=0.f,b3=0.f, la=0.f;
    if (own){
        b0 = bias[ohc]; b1 = bias[HID+ohc]; b2 = bias[2*HID+ohc]; b3 = bias[3*HID+ohc];
        la = log_alpha[ohc];
        float uu = urand[ohc];
        float lg = (logf(uu) - log1pf(-uu) + la)*1.5f;
        s_cur = fminf(fmaxf(1.2f*sigmoidf_(lg) - 0.1f, 0.f), 1.f);
    }
    __syncthreads();

    float accv[6][8];
    alignas(16) float tfA[24];
    alignas(16) float tfB[24];

    for (int t = 0; t < T_STEPS; ++t){
        // ---- prefetch xp + next-step urand (no h dependency; hides latency)
        float xpv0=0.f,xpv1=0.f,xpv2=0.f,xpv3=0.f, uu_next=0.f;
        if (own){
            size_t xr_ = (size_t)t*BATCH + row0 + orow;
            if (mode == 2){
                xpv0 = xpf[xr_*G4H + ohc];
                xpv1 = xpf[xr_*G4H + HID + ohc];
                xpv2 = xpf[xr_*G4H + 2*HID + ohc];
                xpv3 = xpf[xr_*G4H + 3*HID + ohc];
            } else if (mode == 1){
                xpv0 = bf16_to_f32(xpb[xr_*G4H + ohc]);
                xpv1 = bf16_to_f32(xpb[xr_*G4H + HID + ohc]);
                xpv2 = bf16_to_f32(xpb[xr_*G4H + 2*HID + ohc]);
                xpv3 = bf16_to_f32(xpb[xr_*G4H + 3*HID + ohc]);
            }
            if (t+1 < T_STEPS) uu_next = urand[(size_t)(t+1)*HID + ohc];
        }

        #pragma unroll
        for (int j=0;j<6;j++)
            #pragma unroll
            for (int rr=0;rr<8;rr++) accv[j][rr] = 0.f;

        // ---- coherent load of h*s halves (half0 now; half1 prefetched under GEMM0)
        {
            const float* src0 = hb + (size_t)((t&1)*BATCH + row0 + sr)*HID + skb;
            #pragma unroll
            for (int i=0;i<12;i++){
                unsigned long long d = __hip_atomic_load(
                    (unsigned long long*)(void*)(src0) + i,
                    __ATOMIC_RELAXED, __HIP_MEMORY_SCOPE_AGENT);
                tfA[2*i]   = __uint_as_float((unsigned int)d);
                tfA[2*i+1] = __uint_as_float((unsigned int)(d>>32));
            }
        }

        #pragma unroll 1
        for (int half=0; half<2; ++half){
            {   // LDS write of this half
                float* dst = sH + sr*SH_STRIDE + skb;
                const float* tf = half ? tfB : tfA;
                #pragma unroll
                for (int i=0;i<6;i++)
                    *(f32x4*)(dst + 4*i) = *(const f32x4*)(tf + 4*i);
            }
            __syncthreads();
            if (half == 0){ // prefetch half1 (latency hidden behind GEMM half0)
                const float* src1 = hb + (size_t)((t&1)*BATCH + row0 + sr)*HID + 384 + skb;
                #pragma unroll
                for (int i=0;i<12;i++){
                    unsigned long long d = __hip_atomic_load(
                        (unsigned long long*)(void*)(src1) + i,
                        __ATOMIC_RELAXED, __HIP_MEMORY_SCOPE_AGENT);
                    tfB[2*i]   = __uint_as_float((unsigned int)d);
                    tfB[2*i+1] = __uint_as_float((unsigned int)(d>>32));
                }
            }
            {   // GEMM this half: 8 rows x 6 cols per thread, K-chunk 12
                const float* uB = sU + (qg*6)*HID + half*384 + ks*12;
                const float* hB = sH + (rt*8)*SH_STRIDE + ks*12;
                #pragma unroll
                for (int kq=0;kq<3;kq++){
                    f32x4 hv[8];
                    #pragma unroll
                    for (int rr=0;rr<8;rr++) hv[rr] = *(const f32x4*)(hB + rr*SH_STRIDE + kq*4);
                    #pragma unroll
                    for (int j=0;j<6;j++){
                        f32x4 uv = *(const f32x4*)(uB + j*HID + kq*4);
                        #pragma unroll
                        for (int rr=0;rr<8;rr++)
                            accv[j][rr] += hv[rr].x*uv.x + hv[rr].y*uv.y + hv[rr].z*uv.z + hv[rr].w*uv.w;
                    }
                }
            }
            __syncthreads();
        }

        // ---- fallback: fused x @ W^T (same machinery; W streamed from L2)
        if (mode == 0){
            #pragma unroll 1
            for (int half=0; half<2; ++half){
                {   // stage x_t half: 32 rows x 256 k
                    const int xkb = (tid & 15)*16;
                    const float* src = x + ((size_t)t*BATCH + row0 + sr)*IN_DIM + half*256 + xkb;
                    float* dst = sH + sr*SH_STRIDE + xkb;
                    #pragma unroll
                    for (int i=0;i<4;i++)
                        *(f32x4*)(dst + 4*i) = *(const f32x4*)(src + 4*i);
                }
                __syncthreads();
                {
                    const float* hB = sH + (rt*8)*SH_STRIDE + ks*8;
                    const float* wB = W + (size_t)(qg*HID + hc0)*IN_DIM + half*256 + ks*8;
                    #pragma unroll
                    for (int kq=0;kq<2;kq++){
                        f32x4 hv[8];
                        #pragma unroll
                        for (int rr=0;rr<8;rr++) hv[rr] = *(const f32x4*)(hB + rr*SH_STRIDE + kq*4);
                        #pragma unroll
                        for (int j=0;j<6;j++){
                            f32x4 uv = *(const f32x4*)(wB + (size_t)j*IN_DIM + kq*4);
                            #pragma unroll
                            for (int rr=0;rr<8;rr++)
                                accv[j][rr] += hv[rr].x*uv.x + hv[rr].y*uv.y + hv[rr].z*uv.z + hv[rr].w*uv.w;
                        }
                    }
                }
                __syncthreads();
            }
        }

        // ---- reduce K-split partials across the 32 ks lanes (width-32 shuffles)
        #pragma unroll
        for (int j=0;j<6;j++)
            #pragma unroll
            for (int rr=0;rr<8;rr++){
                float v = accv[j][rr];
                v += __shfl_down(v,16,32);
                v += __shfl_down(v, 8,32);
                v += __shfl_down(v, 4,32);
                v += __shfl_down(v, 2,32);
                v += __shfl_down(v, 1,32);
                accv[j][rr] = v;
            }
        if (ks == 0){
            #pragma unroll
            for (int j=0;j<6;j++){
                float* dst = sRed + (qg*6 + j)*32 + rt*8;
                f32x4 w0 = { accv[j][0], accv[j][1], accv[j][2], accv[j][3] };
                f32x4 w1 = { accv[j][4], accv[j][5], accv[j][6], accv[j][7] };
                *(f32x4*)(dst)     = w0;
                *(f32x4*)(dst + 4) = w1;
            }
        }
        __syncthreads();

        // ---- pointwise LSTM update (192 owner lanes)
        if (own){
            float p0 = sRed[(0*6+oj)*32 + orow] + xpv0 + b0;
            float p1 = sRed[(1*6+oj)*32 + orow] + xpv1 + b1;
            float p2 = sRed[(2*6+oj)*32 + orow] + xpv2 + b2;
            float p3 = sRed[(3*6+oj)*32 + orow] + xpv3 + b3;
            float s = s_cur;
            p0*=s; p1*=s; p2*=s; p3*=s;
            float ig = sigmoidf_(p0)*s;
            float fg = sigmoidf_(p1)*s;
            float cg = tanhf(p2)*s;
            float og = sigmoidf_(p3)*s;
            c_state = fg*c_state + ig*cg;
            float h = og*tanhf(c_state);
            out[((size_t)t*BATCH + row0 + orow)*HID + ohc] = h;
            if (t+1 < T_STEPS){
                float lg = (logf(uu_next) - log1pf(-uu_next) + la)*1.5f;
                float sn = fminf(fmaxf(1.2f*sigmoidf_(lg) - 0.1f, 0.f), 1.f);
                __hip_atomic_store(hb + (size_t)(((t+1)&1)*BATCH + row0 + orow)*HID + ohc, h*sn,
                                   __ATOMIC_RELAXED, __HIP_MEMORY_SCOPE_AGENT);
                s_cur = sn;
            }
        }

        // ---- group barrier (128 blocks, 4 striped counters, no cache fences)
        if (t+1 < T_STEPS){
            __syncthreads();   // drains each wave's vmcnt -> h stores at MALL
            if (tid == 0){
                unsigned cell = (unsigned)((bg*4 + (cb&3))*32);
                __hip_atomic_fetch_add(bar + cell, 1u, __ATOMIC_RELAXED, __HIP_MEMORY_SCOPE_AGENT);
                unsigned tgt = (unsigned)(t+1)*128u;
                for (;;){
                    unsigned ssum = 0;
                    #pragma unroll
                    for (int c2=0;c2<4;c2++)
                        ssum += __hip_atomic_load(bar + (bg*4+c2)*32, __ATOMIC_RELAXED, __HIP_MEMORY_SCOPE_AGENT);
                    if (ssum >= tgt) break;
                    __builtin_amdgcn_s_sleep(1);
                }
            }
            __syncthreads();
        }
    }
}

extern "C" void kernel_launch(void* const* d_in, const int* in_sizes, int n_in,
                              void* d_out, int out_size, void* d_ws, size_t ws_size,
                              hipStream_t stream){
    const float* x  = (const float*)d_in[0];
    const float* W  = (const float*)d_in[1];
    const float* U  = (const float*)d_in[2];
    const float* b  = (const float*)d_in[3];
    const float* la = (const float*)d_in[4];
    const float* u  = (const float*)d_in[5];
    float* out = (float*)d_out;

    char* ws = (char*)d_ws;
    float*          hbuf = (float*)ws;                               // 393216 B
    unsigned int*   bar  = (unsigned int*)(ws + 393216);             // 1024 B (pad to 4096)
    unsigned short* xbf  = (unsigned short*)(ws + 397312);           // 33554432 B
    unsigned short* wbf  = (unsigned short*)(ws + 397312 + 33554432);// 3145728 B
    char*           xp   = ws + 37097472;

    const size_t need_bf16 = 37097472ull + 201326592ull;   // ~227 MB
    const size_t need_f32  = 37097472ull + 402653184ull;   // ~419 MB
    int mode = (ws_size >= need_f32) ? 2 : (ws_size >= need_bf16) ? 1 : 0;

    hipMemsetAsync(d_ws, 0, 397312 + 1024, stream);        // zero hbuf + barrier

    if (mode > 0){
        cvt_bf16_kernel<<<65536, 256, 0, stream>>>(x, xbf, 32768*512);
        cvt_bf16_kernel<<<6144,  256, 0, stream>>>(W, wbf, 3072*512);
        xproj_gemm<<<6144, 256, 0, stream>>>(xbf, wbf, (unsigned short*)xp, (float*)xp,
                                             mode == 2 ? 1 : 0);
    }
    masked_lstm_scan2<<<256, 512, 0, stream>>>(x, W, U, b, la, u, out, hbuf, bar,
        (const unsigned short*)xp, (const float*)xp, mode);
}

// Round 3
// 3457.993 us; speedup vs baseline: 19.3962x; 5.5126x over previous
//
#include <hip/hip_runtime.h>
#include <cstdint>
#include <cstddef>

#define T_STEPS 512
#define BATCH   64
#define IN_DIM  512
#define HID     768
#define G4H     3072
#define NROWS   32768        // T*B
// hbuf geometry (bf16 planes, MFMA-A fragment-linear: [kb][kq][m 0..31][j 0..7])
#define PLANE   49152        // bytes per plane (24*4*32*8 elems * 2B)
#define HALFB   24576        // bytes per half-plane (kb 0..11)
#define GRPB    98304        // bytes per group (hi+lo)
#define DBUFB   196608       // bytes per double-buffer slot (2 groups)

typedef __attribute__((ext_vector_type(8))) short bf16x8;
typedef __attribute__((ext_vector_type(4))) float f32x4;

__device__ __forceinline__ float sigmoidf_(float z){ return 1.0f/(1.0f+expf(-z)); }
__device__ __forceinline__ float bf16_to_f32(unsigned short u){
    return __uint_as_float(((unsigned int)u) << 16);
}
__device__ __forceinline__ unsigned short f32_to_bf16_rne(float v){
    unsigned int bits = __float_as_uint(v);
    unsigned int lsb = (bits >> 16) & 1u;
    bits += 0x7fffu + lsb;
    return (unsigned short)(bits >> 16);
}

// ---------------- phase 1a: fp32 -> bf16 ----------------
__global__ void cvt_bf16_kernel(const float* __restrict__ in, unsigned short* __restrict__ out, int n){
    int i = blockIdx.x*256 + threadIdx.x;
    if (i < n) out[i] = f32_to_bf16_rne(in[i]);
}

// ---------------- phase 1b: xpT[col][trow] = (x @ W^T)^T, bf16 ----------------
// A = xbf [32768 x 512], B = wbf [3072 x 512]. Transposed store: owner lanes in
// the scan read 32 consecutive trows per gate-col (coalesced 2B loads).
__global__ __launch_bounds__(256, 4) void xproj_gemm_t(
    const unsigned short* __restrict__ A, const unsigned short* __restrict__ B,
    unsigned short* __restrict__ CT)
{
    const int wave = threadIdx.x >> 6;
    const int lane = threadIdx.x & 63;
    const int tile = blockIdx.x*4 + wave;         // 24576 = 512 x 48
    const int mt = tile & 511;
    const int nt = tile >> 9;
    const long m0 = (long)mt*64, n0 = (long)nt*64;
    const int lr = lane & 15, lq = lane >> 4;

    f32x4 acc[4][4];
    #pragma unroll
    for (int i=0;i<4;i++)
        #pragma unroll
        for (int j=0;j<4;j++) acc[i][j] = (f32x4){0.f,0.f,0.f,0.f};

    const unsigned short* Ap = A + (m0 + lr)*512 + lq*8;
    const unsigned short* Bp = B + (n0 + lr)*512 + lq*8;

    for (int k0 = 0; k0 < 512; k0 += 32){
        bf16x8 a[4], b[4];
        #pragma unroll
        for (int i=0;i<4;i++) a[i] = *(const bf16x8*)(Ap + (long)i*16*512 + k0);
        #pragma unroll
        for (int j=0;j<4;j++) b[j] = *(const bf16x8*)(Bp + (long)j*16*512 + k0);
        #pragma unroll
        for (int i=0;i<4;i++)
            #pragma unroll
            for (int j=0;j<4;j++)
                acc[i][j] = __builtin_amdgcn_mfma_f32_16x16x32_bf16(a[i], b[j], acc[i][j], 0,0,0);
    }

    // C row=(lane>>4)*4+reg (M), col=lane&15 (N). One wave fully dirties each
    // 128B xpT line (64 trows per col) -> clean write-back, no amplification.
    #pragma unroll
    for (int i=0;i<4;i++)
        #pragma unroll
        for (int j=0;j<4;j++){
            long col = n0 + 16*j + lr;
            long rb  = m0 + 16*i + lq*4;
            unsigned long long pk =
                  (unsigned long long)f32_to_bf16_rne(acc[i][j][0])
                | ((unsigned long long)f32_to_bf16_rne(acc[i][j][1]) << 16)
                | ((unsigned long long)f32_to_bf16_rne(acc[i][j][2]) << 32)
                | ((unsigned long long)f32_to_bf16_rne(acc[i][j][3]) << 48);
            *(unsigned long long*)(CT + col*NROWS + rb) = pk;
        }
}

// ---------------- phase 2: persistent scan ----------------
// 256 blocks x 512 threads (8 waves). bg=bx&1: batch half (32 rows); cb=bx>>1
// owns 6 h-cols (24 gate-cols, padded to 32 for 2 N-tiles of 16).
// Waves: ks2=w&1 (K-split), mt=(w>>1)&1 (M-tile), nt=w>>2 (N-tile).
// U slice: split-bf16 (hi+lo) B-fragments held in VGPRs for all 512 steps.
// h exchange: uncached (sc0 sc1) loads/stores of fragment-linear bf16 planes.
__global__ __launch_bounds__(512, 2) void lstm_scan3(
    const float* __restrict__ U,
    const float* __restrict__ bias,
    const float* __restrict__ log_alpha,
    const float* __restrict__ urand,
    const unsigned short* __restrict__ xpT,
    float* __restrict__ out,
    char* __restrict__ hbuf,            // 2 dbuf x 2 grp x 98304 B
    unsigned int* __restrict__ bar)
{
    __shared__ short sH[49152];         // 98304 B: hi plane elems [0,24576), lo [24576,49152)
    __shared__ float sRed[32*36 + 4];   // gate preacts [c][row], stride 36

    const int tid = threadIdx.x;
    const int bx  = blockIdx.x;
    const int bg  = bx & 1;
    const int cb  = bx >> 1;             // 0..127
    const int hc0 = 6*cb;
    const int row0 = 32*bg;

    const int w    = tid >> 6;
    const int lane = tid & 63;
    const int ks2  = w & 1;
    const int mt   = (w >> 1) & 1;
    const int nt   = w >> 2;
    const int lr   = lane & 15;
    const int kq   = lane >> 4;
    const int mrow = mt*16 + lr;

    // ---- B fragments (U slice) -> VGPRs, split bf16 hi+lo, once ----
    bf16x8 Bh[12], Bl[12];
    {
        const int c = nt*16 + lr;        // gate-col within block (0..31; >=24 = pad)
        for (int i=0;i<12;i++){
            int kb = (i<6) ? (ks2*6 + i) : (12 + ks2*6 + (i-6));
            bf16x8 bh = {0,0,0,0,0,0,0,0};
            bf16x8 bl = {0,0,0,0,0,0,0,0};
            if (c < 24){
                int g = c/6, jj = c - 6*g;
                const float* up = U + (size_t)(g*HID + hc0 + jj)*HID + kb*32 + kq*8;
                #pragma unroll
                for (int e=0;e<8;e++){
                    float v = up[e];
                    unsigned short hu = f32_to_bf16_rne(v);
                    unsigned short lu = f32_to_bf16_rne(v - bf16_to_f32(hu));
                    bh[e] = (short)hu; bl[e] = (short)lu;
                }
            }
            Bh[i]=bh; Bl[i]=bl;
        }
    }

    // ---- owner-lane state (tid<192 = waves 0..2; orow=tid&31, oj=tid>>5) ----
    const bool own = tid < 192;
    const int orow = tid & 31;
    const int oj   = tid >> 5;
    const int ohc  = hc0 + (oj < 6 ? oj : 0);
    float c_state = 0.f, s_cur = 0.f;
    float b0=0.f,b1=0.f,b2=0.f,b3=0.f, la=0.f;
    if (own){
        b0 = bias[ohc]; b1 = bias[HID+ohc]; b2 = bias[2*HID+ohc]; b3 = bias[3*HID+ohc];
        la = log_alpha[ohc];
        float uu = urand[ohc];
        float lg = (logf(uu) - log1pf(-uu) + la)*1.5f;
        s_cur = fminf(fmaxf(1.2f*sigmoidf_(lg) - 0.1f, 0.f), 1.f);
    }
    __syncthreads();

    const short* sHhi = sH;
    const short* sHlo = sH + 24576;

#define ISSUE(ri, ii, hs_) do{ \
        int ch_ = tid + (ii)*512; int sg_ = (ch_ >= 1536); int of_ = ch_ - sg_*1536; \
        const char* p_ = gsrc + sg_*PLANE + (hs_)*HALFB + of_*16; \
        asm volatile("global_load_dwordx4 %0, %1, off sc0 sc1" : "=v"(ri) : "v"(p_)); \
    }while(0)
#define DSW(ri, ii, hs_) do{ \
        int ch_ = tid + (ii)*512; int sg_ = (ch_ >= 1536); int of_ = ch_ - sg_*1536; \
        *(f32x4*)((char*)sH + sg_*PLANE + (hs_)*HALFB + of_*16) = ri; \
    }while(0)

    for (int t = 0; t < T_STEPS; ++t){
        const char* gsrc = hbuf + (size_t)(t&1)*DBUFB + (size_t)bg*GRPB;

        // owner prefetch (cached; latency hidden under staging+MFMA)
        float xv0=0.f,xv1=0.f,xv2=0.f,xv3=0.f, uun=0.f;
        if (own){
            size_t trow = (size_t)t*BATCH + row0 + orow;
            xv0 = bf16_to_f32(xpT[(size_t)(0*HID+ohc)*NROWS + trow]);
            xv1 = bf16_to_f32(xpT[(size_t)(1*HID+ohc)*NROWS + trow]);
            xv2 = bf16_to_f32(xpT[(size_t)(2*HID+ohc)*NROWS + trow]);
            xv3 = bf16_to_f32(xpT[(size_t)(3*HID+ohc)*NROWS + trow]);
            if (t+1 < T_STEPS) uun = urand[(size_t)(t+1)*HID + ohc];
        }

        f32x4 r0,r1,r2,r3,r4,r5;
        // half0: issue uncached loads, wait, stage to LDS
        ISSUE(r0,0,0); ISSUE(r1,1,0); ISSUE(r2,2,0);
        ISSUE(r3,3,0); ISSUE(r4,4,0); ISSUE(r5,5,0);
        asm volatile("s_waitcnt vmcnt(0)"
            : "+v"(r0),"+v"(r1),"+v"(r2),"+v"(r3),"+v"(r4),"+v"(r5) :: "memory");
        DSW(r0,0,0); DSW(r1,1,0); DSW(r2,2,0);
        DSW(r3,3,0); DSW(r4,4,0); DSW(r5,5,0);
        // half1: issue now, consume after phase E (latency overlapped)
        ISSUE(r0,0,1); ISSUE(r1,1,1); ISSUE(r2,2,1);
        ISSUE(r3,3,1); ISSUE(r4,4,1); ISSUE(r5,5,1);
        __syncthreads();

        // phase E: kb in [ks2*6, ks2*6+6)  (half0). Two acc chains for ILP.
        f32x4 acc0 = {0.f,0.f,0.f,0.f};
        f32x4 acc1 = {0.f,0.f,0.f,0.f};
        #pragma unroll
        for (int i=0;i<6;i++){
            int kb = ks2*6 + i;
            int eo = ((kb*4 + kq)*32 + mrow)*8;
            bf16x8 ah = *(const bf16x8*)(sHhi + eo);
            bf16x8 al = *(const bf16x8*)(sHlo + eo);
            acc0 = __builtin_amdgcn_mfma_f32_16x16x32_bf16(ah, Bh[i], acc0, 0,0,0);
            acc1 = __builtin_amdgcn_mfma_f32_16x16x32_bf16(al, Bh[i], acc1, 0,0,0);
            acc1 = __builtin_amdgcn_mfma_f32_16x16x32_bf16(ah, Bl[i], acc1, 0,0,0);
        }
        // stage half1 (disjoint LDS region; no race with half0 readers)
        asm volatile("s_waitcnt vmcnt(0)"
            : "+v"(r0),"+v"(r1),"+v"(r2),"+v"(r3),"+v"(r4),"+v"(r5) :: "memory");
        DSW(r0,0,1); DSW(r1,1,1); DSW(r2,2,1);
        DSW(r3,3,1); DSW(r4,4,1); DSW(r5,5,1);
        __syncthreads();

        // phase G: kb in [12+ks2*6, 12+ks2*6+6)  (half1)
        #pragma unroll
        for (int i=0;i<6;i++){
            int kb = 12 + ks2*6 + i;
            int eo = ((kb*4 + kq)*32 + mrow)*8;
            bf16x8 ah = *(const bf16x8*)(sHhi + eo);
            bf16x8 al = *(const bf16x8*)(sHlo + eo);
            acc0 = __builtin_amdgcn_mfma_f32_16x16x32_bf16(ah, Bh[6+i], acc0, 0,0,0);
            acc1 = __builtin_amdgcn_mfma_f32_16x16x32_bf16(al, Bh[6+i], acc1, 0,0,0);
            acc1 = __builtin_amdgcn_mfma_f32_16x16x32_bf16(ah, Bl[6+i], acc1, 0,0,0);
        }
        f32x4 acc = acc0 + acc1;

        // C combine across the 2 K-split waves (two-pass through sRed)
        {
            int c = nt*16 + lr;
            float* rp = sRed + c*36 + mt*16 + kq*4;
            if (ks2 == 0 && c < 24) *(f32x4*)rp = acc;
            __syncthreads();
            if (ks2 == 1 && c < 24){
                f32x4 o = *(const f32x4*)rp;
                o += acc;
                *(f32x4*)rp = o;
            }
            __syncthreads();
        }

        // pointwise LSTM update (owner lanes)
        if (own){
            float p0 = sRed[(0*6+oj)*36 + orow] + xv0 + b0;
            float p1 = sRed[(1*6+oj)*36 + orow] + xv1 + b1;
            float p2 = sRed[(2*6+oj)*36 + orow] + xv2 + b2;
            float p3 = sRed[(3*6+oj)*36 + orow] + xv3 + b3;
            float s = s_cur;
            p0*=s; p1*=s; p2*=s; p3*=s;
            float ig = sigmoidf_(p0)*s;
            float fg = sigmoidf_(p1)*s;
            float cg = tanhf(p2)*s;
            float og = sigmoidf_(p3)*s;
            c_state = fg*c_state + ig*cg;
            float h = og*tanhf(c_state);
            out[((size_t)t*BATCH + row0 + orow)*HID + ohc] = h;
            if (t+1 < T_STEPS){
                float lg = (logf(uun) - log1pf(-uun) + la)*1.5f;
                float sn = fminf(fmaxf(1.2f*sigmoidf_(lg) - 0.1f, 0.f), 1.f);
                float hs = h * sn;
                unsigned short hh = f32_to_bf16_rne(hs);
                unsigned short hl = f32_to_bf16_rne(hs - bf16_to_f32(hh));
                char* dst = hbuf + (size_t)((t+1)&1)*DBUFB + (size_t)bg*GRPB;
                int eo = (( (ohc>>5)*4 + ((ohc>>3)&3) )*32 + orow)*8 + (ohc&7);
                unsigned int vh = hh, vl = hl;
                asm volatile("global_store_short %0, %1, off sc0 sc1"
                             :: "v"(dst + 2*(size_t)eo), "v"(vh) : "memory");
                asm volatile("global_store_short %0, %1, off sc0 sc1"
                             :: "v"(dst + PLANE + 2*(size_t)eo), "v"(vl) : "memory");
                s_cur = sn;
            }
        }

        // grid barrier (128 blocks per group, 4 striped counters, no L2 fences)
        if (t+1 < T_STEPS){
            asm volatile("s_waitcnt vmcnt(0)" ::: "memory");  // h stores at MALL
            __syncthreads();
            if (tid == 0){
                unsigned cell = (unsigned)((bg*4 + (cb&3))*32);
                __hip_atomic_fetch_add(bar + cell, 1u, __ATOMIC_RELAXED, __HIP_MEMORY_SCOPE_AGENT);
                unsigned tgt = (unsigned)(t+1)*128u;
                for (;;){
                    unsigned ssum = 0;
                    #pragma unroll
                    for (int c2=0;c2<4;c2++)
                        ssum += __hip_atomic_load(bar + (bg*4+c2)*32, __ATOMIC_RELAXED, __HIP_MEMORY_SCOPE_AGENT);
                    if (ssum >= tgt) break;
                    __builtin_amdgcn_s_sleep(1);
                }
            }
            __syncthreads();
        }
    }
#undef ISSUE
#undef DSW
}

extern "C" void kernel_launch(void* const* d_in, const int* in_sizes, int n_in,
                              void* d_out, int out_size, void* d_ws, size_t ws_size,
                              hipStream_t stream){
    const float* x  = (const float*)d_in[0];
    const float* W  = (const float*)d_in[1];
    const float* U  = (const float*)d_in[2];
    const float* b  = (const float*)d_in[3];
    const float* la = (const float*)d_in[4];
    const float* u  = (const float*)d_in[5];
    float* out = (float*)d_out;

    char* ws = (char*)d_ws;
    char*           hbuf = ws;                                        // 393216 B
    unsigned int*   bar  = (unsigned int*)(ws + 393216);              // 1024 B used
    unsigned short* xbf  = (unsigned short*)(ws + 397312);            // 33554432 B
    unsigned short* wbf  = (unsigned short*)(ws + 397312 + 33554432); // 3145728 B
    unsigned short* xpT  = (unsigned short*)(ws + 37097472);          // 201326592 B
    // total 238424064 B — proven to fit (round 2 ran the bf16-xp path)

    hipMemsetAsync(d_ws, 0, 397312, stream);   // zero hbuf (h0=0) + barrier

    cvt_bf16_kernel<<<65536, 256, 0, stream>>>(x, xbf, NROWS*IN_DIM);
    cvt_bf16_kernel<<<6144,  256, 0, stream>>>(W, wbf, G4H*IN_DIM);
    xproj_gemm_t<<<6144, 256, 0, stream>>>(xbf, wbf, xpT);
    lstm_scan3<<<256, 512, 0, stream>>>(U, b, la, u, xpT, out, hbuf, bar);
}